// Round 1
// baseline (488.304 us; speedup 1.0000x reference)
//
#include <hip/hip_runtime.h>

typedef __bf16 bf16;
typedef __attribute__((ext_vector_type(4))) float f32x4;
typedef __attribute__((ext_vector_type(8))) __bf16 bf16x8;
typedef __attribute__((ext_vector_type(4))) __bf16 bf16x4;
typedef __attribute__((ext_vector_type(4))) int i32x4;

#define NN 8192
#define FI 512
#define FO 256
#define NSPLIT 4
#define JCHUNK (NN / NSPLIT)

// ---------------------------------------------------------------------------
// K1: Wh = h @ W + bW (fp32 VALU tiled GEMM, 64x64 tiles, 4x4 per thread).
// Writes Whb in bf16, fragment-major layout [j/32][n][j%32] (so K4's B-tile
// staging is one fully-coalesced contiguous 16KB block per j-tile), and
// accumulates f1 = Wh@a1, f2 = Wh@a2 via global atomics (f1/f2 pre-zeroed).
// ---------------------------------------------------------------------------
__global__ __launch_bounds__(256) void k1_gemm(
    const float* __restrict__ h, const float* __restrict__ W,
    const float* __restrict__ bW, const float* __restrict__ a1,
    const float* __restrict__ a2, bf16* __restrict__ whb,
    float* __restrict__ f1, float* __restrict__ f2) {
  __shared__ float As[16][68];  // [k][row] (transposed so inner loop reads float4)
  __shared__ float Bs[16][72];  // [k][col]
  const int t = threadIdx.x;
  const int bi = blockIdx.x, bj = blockIdx.y;
  const int tx = t & 15, ty = t >> 4;
  const int lr = t >> 2, lc = (t & 3) * 4;   // h staging: row, k-offset
  const int wr = t >> 4, wc = (t & 15) * 4;  // W staging: k-row, col-offset
  float acc[4][4] = {};
  const float* hrow = h + (size_t)(bi * 64 + lr) * FI;
  for (int kt = 0; kt < FI / 16; ++kt) {
    f32x4 hv = *(const f32x4*)(hrow + kt * 16 + lc);
    f32x4 wv = *(const f32x4*)(W + (size_t)(kt * 16 + wr) * FO + bj * 64 + wc);
    __syncthreads();
    As[lc + 0][lr] = hv.x; As[lc + 1][lr] = hv.y;
    As[lc + 2][lr] = hv.z; As[lc + 3][lr] = hv.w;
    *(f32x4*)&Bs[wr][wc] = wv;
    __syncthreads();
#pragma unroll
    for (int k = 0; k < 16; ++k) {
      f32x4 av = *(const f32x4*)&As[k][ty * 4];
      f32x4 bv = *(const f32x4*)&Bs[k][tx * 4];
#pragma unroll
      for (int r = 0; r < 4; ++r)
#pragma unroll
        for (int cc = 0; cc < 4; ++cc)
          acc[r][cc] += av[r] * bv[cc];
    }
  }
  const int i0 = bi * 64 + ty * 4;
  const int n0 = bj * 64 + tx * 4;
  float f1p[4] = {}, f2p[4] = {};
#pragma unroll
  for (int r = 0; r < 4; ++r) {
    const int i = i0 + r;
#pragma unroll
    for (int cc = 0; cc < 4; ++cc) {
      const int n = n0 + cc;
      float wh = acc[r][cc] + bW[n];
      whb[(size_t)(i >> 5) * (FO * 32) + n * 32 + (i & 31)] = (bf16)wh;
      f1p[r] += wh * a1[n];
      f2p[r] += wh * a2[n];
    }
  }
#pragma unroll
  for (int m = 1; m < 16; m <<= 1) {
#pragma unroll
    for (int r = 0; r < 4; ++r) {
      f1p[r] += __shfl_xor(f1p[r], m);
      f2p[r] += __shfl_xor(f2p[r], m);
    }
  }
  if (tx == 0) {
#pragma unroll
    for (int r = 0; r < 4; ++r) {
      atomicAdd(&f1[i0 + r], f1p[r]);
      atomicAdd(&f2[i0 + r], f2p[r]);
    }
  }
}

// ---------------------------------------------------------------------------
// K3: Mstar = max_j f2[j] (global upper bound for the per-row softmax shift).
// ---------------------------------------------------------------------------
__global__ __launch_bounds__(256) void k3_max(const float* __restrict__ f2,
                                              float* __restrict__ Mstar) {
  __shared__ float red[4];
  const int t = threadIdx.x;
  float m = -1e30f;
  for (int i = t; i < NN; i += 256) m = fmaxf(m, f2[i]);
#pragma unroll
  for (int d = 1; d < 64; d <<= 1) m = fmaxf(m, __shfl_xor(m, d));
  if ((t & 63) == 0) red[t >> 6] = m;
  __syncthreads();
  if (t == 0) *Mstar = fmaxf(fmaxf(red[0], red[1]), fmaxf(red[2], red[3]));
}

// ---------------------------------------------------------------------------
// K4: fused masked-softmax GEMM partial:
//   acc_part[s][i][:] = sum_{j in chunk s} P(i,j) * Wh[j][:]
//   l_part[s][i]      = sum_{j in chunk s} P(i,j)
// with P(i,j) = adj ? exp(LR(c_i + f2_j) - shift_i) : 0 (shift via global max,
// so partials across s-chunks add directly — no online rescale needed).
// Block: 256 thr (4 waves), BM=32 rows x all 256 cols, K-step = 32 j.
// MFMA 16x16x32 bf16; A = P-tile (LDS, row-major pad 40), B = Wh-tile (LDS,
// [n][k] pad 40, staged from fragment-major global layout, fully coalesced).
// ---------------------------------------------------------------------------
__global__ __launch_bounds__(256) void k4_attn(
    const int* __restrict__ adj, const bf16* __restrict__ whb,
    const float* __restrict__ f1, const float* __restrict__ f2,
    const float* __restrict__ Mstar, const float* __restrict__ ba_p,
    float* __restrict__ acc_part, float* __restrict__ l_part) {
  __shared__ bf16 Pl[32 * 40];
  __shared__ bf16 Bl[256 * 40];
  const int t = threadIdx.x;
  const int lane = t & 63, w = t >> 6;
  const int rb = blockIdx.x, s = blockIdx.y;
  const int i0 = rb * 32;
  const int rloc = t >> 3;          // row this thread scores (0..31)
  const int jj = (t & 7) * 4;       // 4 j's within the 32-wide k-step
  const int m16 = lane & 15, q = lane >> 4;

  const float ba = *ba_p;
  const float Ms = *Mstar;
  const float ci = f1[i0 + rloc] + ba;
  float sh = ci + Ms;
  sh = fmaxf(sh, 0.2f * sh);        // LeakyReLU(c_i + Mstar) >= row max

  const f32x4 z4 = {0.f, 0.f, 0.f, 0.f};
  f32x4 acc0[4], acc1[4];
#pragma unroll
  for (int cc = 0; cc < 4; ++cc) { acc0[cc] = z4; acc1[cc] = z4; }
  float lreg = 0.f;

  const int* adjrow = adj + (size_t)(i0 + rloc) * NN;

  for (int kt = 0; kt < JCHUNK / 32; ++kt) {
    const int j0 = s * JCHUNK + kt * 32;
    // --- global loads (before barrier, overlap with prev MFMA) ---
    i32x4 a4 = *(const i32x4*)(adjrow + j0 + jj);
    f32x4 s4 = *(const f32x4*)(f2 + j0 + jj);
    const size_t jt_base = (size_t)(j0 >> 5) * (FO * 32);
    bf16x8 bstg[4];
#pragma unroll
    for (int u = 0; u < 4; ++u)
      bstg[u] = *(const bf16x8*)(whb + jt_base + (size_t)(t + 256 * u) * 8);
    float pv[4];
#pragma unroll
    for (int x = 0; x < 4; ++x) {
      float arg = ci + s4[x];
      float e = fmaxf(arg, 0.2f * arg);            // LeakyReLU, slope 0.2
      pv[x] = (a4[x] > 0) ? __expf(e - sh) : 0.f;  // masked, in (0,1]
    }
    lreg += pv[0] + pv[1] + pv[2] + pv[3];
    __syncthreads();  // previous iteration's fragment reads done
    bf16x4 pb = {(bf16)pv[0], (bf16)pv[1], (bf16)pv[2], (bf16)pv[3]};
    *(bf16x4*)&Pl[rloc * 40 + jj] = pb;
#pragma unroll
    for (int u = 0; u < 4; ++u) {
      const int tt = t + 256 * u;
      *(bf16x8*)&Bl[(tt >> 2) * 40 + (tt & 3) * 8] = bstg[u];
    }
    __syncthreads();
    // --- MFMA: A[m=lane&15][k=q*8+j], B[k=q*8+j][n=lane&15] ---
    bf16x8 af0 = *(const bf16x8*)&Pl[m16 * 40 + q * 8];
    bf16x8 af1 = *(const bf16x8*)&Pl[(16 + m16) * 40 + q * 8];
#pragma unroll
    for (int cc = 0; cc < 4; ++cc) {
      bf16x8 bfr = *(const bf16x8*)&Bl[((w * 4 + cc) * 16 + m16) * 40 + q * 8];
      acc0[cc] = __builtin_amdgcn_mfma_f32_16x16x32_bf16(af0, bfr, acc0[cc], 0, 0, 0);
      acc1[cc] = __builtin_amdgcn_mfma_f32_16x16x32_bf16(af1, bfr, acc1[cc], 0, 0, 0);
    }
  }
  // rowsum partial: reduce the 8 threads sharing a row
  lreg += __shfl_xor(lreg, 1);
  lreg += __shfl_xor(lreg, 2);
  lreg += __shfl_xor(lreg, 4);
  if ((t & 7) == 0) l_part[(size_t)s * NN + i0 + rloc] = lreg;
  // C/D layout: col = lane&15, row = (lane>>4)*4 + reg  [verified m89/m91]
  float* ap = acc_part + (size_t)s * ((size_t)NN * FO);
#pragma unroll
  for (int cc = 0; cc < 4; ++cc) {
    const int n = (w * 4 + cc) * 16 + m16;
#pragma unroll
    for (int reg = 0; reg < 4; ++reg) {
      const int r0 = i0 + q * 4 + reg;
      ap[(size_t)r0 * FO + n] = acc0[cc][reg];
      ap[(size_t)(r0 + 16) * FO + n] = acc1[cc][reg];
    }
  }
}

// ---------------------------------------------------------------------------
// K5: out[i][n] = (sum_s acc_part[s][i][n]) / (sum_s l_part[s][i])
// ---------------------------------------------------------------------------
__global__ __launch_bounds__(256) void k5_reduce(
    const float* __restrict__ accp, const float* __restrict__ lp,
    float* __restrict__ out) {
  const int idx = blockIdx.x * 256 + threadIdx.x;
  const int i = idx >> 6, n4 = (idx & 63) * 4;
  f32x4 sum = {0.f, 0.f, 0.f, 0.f};
  float l = 0.f;
#pragma unroll
  for (int s = 0; s < NSPLIT; ++s) {
    sum += *(const f32x4*)&accp[(size_t)s * ((size_t)NN * FO) + (size_t)i * FO + n4];
    l += lp[s * NN + i];
  }
  const float rl = 1.0f / l;
  f32x4 o = sum * rl;
  *(f32x4*)&out[(size_t)i * FO + n4] = o;
}

// ---------------------------------------------------------------------------
// Workspace layout (bytes):
//   [0, 4MB)            whb   : bf16 Wh, fragment-major
//   [4MB, +32KB)        f1
//   [+32KB, +32KB)      f2
//   [+64KB, +256B)      Mstar
//   [.., +32MB)         acc_part[4][8192][256] fp32
//   [.., +128KB)        l_part[4][8192] fp32
// total ~36.2 MB
// ---------------------------------------------------------------------------
extern "C" void kernel_launch(void* const* d_in, const int* in_sizes, int n_in,
                              void* d_out, int out_size, void* d_ws, size_t ws_size,
                              hipStream_t stream) {
  const float* h  = (const float*)d_in[0];
  const int*   adj = (const int*)d_in[1];
  const float* W  = (const float*)d_in[2];
  const float* bW = (const float*)d_in[3];
  const float* a1 = (const float*)d_in[4];
  const float* a2 = (const float*)d_in[5];
  const float* ba = (const float*)d_in[6];
  float* out = (float*)d_out;

  char* ws = (char*)d_ws;
  bf16* whb  = (bf16*)ws;                                   // 4 MB
  float* f1  = (float*)(ws + 4u * 1024 * 1024);             // 32 KB
  float* f2  = (float*)(ws + 4u * 1024 * 1024 + 32 * 1024); // 32 KB
  float* Mst = (float*)(ws + 4u * 1024 * 1024 + 64 * 1024); // 256 B pad
  float* accp = (float*)(ws + 4u * 1024 * 1024 + 64 * 1024 + 256);
  float* lp   = accp + (size_t)NSPLIT * NN * FO;

  hipMemsetAsync(f1, 0, 64 * 1024, stream);  // zero f1+f2 (atomic targets)

  k1_gemm<<<dim3(NN / 64, FO / 64), 256, 0, stream>>>(h, W, bW, a1, a2, whb, f1, f2);
  k3_max<<<1, 256, 0, stream>>>(f2, Mst);
  k4_attn<<<dim3(NN / 32, NSPLIT), 256, 0, stream>>>(adj, whb, f1, f2, Mst, ba, accp, lp);
  k5_reduce<<<(NN * FO / 4) / 256, 256, 0, stream>>>(accp, lp, out);
}

// Round 2
// 481.351 us; speedup vs baseline: 1.0144x; 1.0144x over previous
//
#include <hip/hip_runtime.h>

typedef __bf16 bf16;
typedef __attribute__((ext_vector_type(4))) float f32x4;
typedef __attribute__((ext_vector_type(8))) __bf16 bf16x8;
typedef __attribute__((ext_vector_type(4))) __bf16 bf16x4;
typedef __attribute__((ext_vector_type(4))) int i32x4;

#define NN 8192
#define FI 512
#define FO 256
#define NSPLIT 4
#define JCHUNK (NN / NSPLIT)

// ---------------------------------------------------------------------------
// k0: pack adj (int32, 268 MB) -> bitmask (uint32, 8 MB). Pure streaming:
// each thread handles 32 consecutive j of one row (8 x i32x4 loads, 1 store).
// 8192 blocks = 32/CU -> enough TLP to stream at ~6 TB/s.
// ---------------------------------------------------------------------------
__global__ __launch_bounds__(256) void k0_pack(const int* __restrict__ adj,
                                               unsigned* __restrict__ mask) {
  const int gid = blockIdx.x * 256 + threadIdx.x;  // 8192*256 threads
  const int* p = adj + (size_t)gid * 32;
  unsigned m = 0;
#pragma unroll
  for (int u = 0; u < 8; ++u) {
    i32x4 v = *(const i32x4*)(p + u * 4);
    m |= (unsigned)(v.x > 0) << (u * 4 + 0);
    m |= (unsigned)(v.y > 0) << (u * 4 + 1);
    m |= (unsigned)(v.z > 0) << (u * 4 + 2);
    m |= (unsigned)(v.w > 0) << (u * 4 + 3);
  }
  mask[gid] = m;
}

// ---------------------------------------------------------------------------
// kw: W [512][256] f32 -> Wt_hi/Wt_lo [256][512] bf16 (transposed + split),
// so k1 can load B fragments straight from global (bf16x8 per lane).
// ---------------------------------------------------------------------------
__global__ __launch_bounds__(256) void kw_split(const float* __restrict__ W,
                                                bf16* __restrict__ wth,
                                                bf16* __restrict__ wtl) {
  const int idx = blockIdx.x * 256 + threadIdx.x;  // 512*256 = 131072
  const int k = idx >> 8, n = idx & 255;
  float x = W[idx];
  bf16 hi = (bf16)x;
  wth[(size_t)n * FI + k] = hi;
  wtl[(size_t)n * FI + k] = (bf16)(x - (float)hi);
}

// ---------------------------------------------------------------------------
// k1: Wh = h @ W + bW via split-bf16 MFMA (hi*hi + hi*lo + lo*hi, fp32 acc;
// rel err ~2^-16). Block = 32 rows x 128 cols, grid (256,2) = 512 blocks.
// A (h tile) split hi/lo in LDS; B fragments direct from Wt_hi/Wt_lo global.
// Writes whb bf16 fragment-major [i/32][n][i%32]; atomically accumulates
// f1 = Wh@a1, f2 = Wh@a2 (pre-zeroed).
// ---------------------------------------------------------------------------
__global__ __launch_bounds__(256) void k1_gemm(
    const float* __restrict__ h, const bf16* __restrict__ wth,
    const bf16* __restrict__ wtl, const float* __restrict__ bW,
    const float* __restrict__ a1, const float* __restrict__ a2,
    bf16* __restrict__ whb, float* __restrict__ f1, float* __restrict__ f2) {
  __shared__ bf16 Ah[32 * 40];
  __shared__ bf16 Al[32 * 40];
  const int t = threadIdx.x;
  const int lane = t & 63, w = t >> 6;
  const int m16 = lane & 15, q = lane >> 4;
  const int bi = blockIdx.x, bj = blockIdx.y;
  const int i0 = bi * 32;
  const int n0 = bj * 128 + w * 32;
  const int srow = t >> 3, skoff = (t & 7) * 4;  // A staging: 1 f32x4/thread

  const f32x4 z4 = {0.f, 0.f, 0.f, 0.f};
  f32x4 acc[2][2];  // [mt][nt]
#pragma unroll
  for (int mt = 0; mt < 2; ++mt)
#pragma unroll
    for (int nt = 0; nt < 2; ++nt) acc[mt][nt] = z4;

  const float* hrow = h + (size_t)(i0 + srow) * FI + skoff;

  for (int kt = 0; kt < FI / 32; ++kt) {
    f32x4 hv = *(const f32x4*)(hrow + kt * 32);
    bf16x8 bh[2], bl[2];
#pragma unroll
    for (int nt = 0; nt < 2; ++nt) {
      const size_t woff = (size_t)(n0 + nt * 16 + m16) * FI + kt * 32 + q * 8;
      bh[nt] = *(const bf16x8*)(wth + woff);
      bl[nt] = *(const bf16x8*)(wtl + woff);
    }
    bf16x4 hh, hl;
#pragma unroll
    for (int x = 0; x < 4; ++x) {
      float v = hv[x];
      bf16 hi = (bf16)v;
      hh[x] = hi;
      hl[x] = (bf16)(v - (float)hi);
    }
    __syncthreads();
    *(bf16x4*)&Ah[srow * 40 + skoff] = hh;
    *(bf16x4*)&Al[srow * 40 + skoff] = hl;
    __syncthreads();
#pragma unroll
    for (int mt = 0; mt < 2; ++mt) {
      bf16x8 ah = *(const bf16x8*)&Ah[(mt * 16 + m16) * 40 + q * 8];
      bf16x8 al = *(const bf16x8*)&Al[(mt * 16 + m16) * 40 + q * 8];
#pragma unroll
      for (int nt = 0; nt < 2; ++nt) {
        acc[mt][nt] = __builtin_amdgcn_mfma_f32_16x16x32_bf16(ah, bh[nt], acc[mt][nt], 0, 0, 0);
        acc[mt][nt] = __builtin_amdgcn_mfma_f32_16x16x32_bf16(al, bh[nt], acc[mt][nt], 0, 0, 0);
        acc[mt][nt] = __builtin_amdgcn_mfma_f32_16x16x32_bf16(ah, bl[nt], acc[mt][nt], 0, 0, 0);
      }
    }
  }
  // Epilogue: C/D layout col=lane&15 (n), row=q*4+reg (i within tile).
  float f1p[2][4] = {}, f2p[2][4] = {};
#pragma unroll
  for (int nt = 0; nt < 2; ++nt) {
    const int n = n0 + nt * 16 + m16;
    const float bw = bW[n], av1 = a1[n], av2 = a2[n];
#pragma unroll
    for (int mt = 0; mt < 2; ++mt) {
#pragma unroll
      for (int reg = 0; reg < 4; ++reg) {
        float wh = acc[mt][nt][reg] + bw;
        const int il = mt * 16 + q * 4 + reg;  // i & 31
        whb[(size_t)bi * (FO * 32) + n * 32 + il] = (bf16)wh;
        f1p[mt][reg] += wh * av1;
        f2p[mt][reg] += wh * av2;
      }
    }
  }
#pragma unroll
  for (int m = 1; m < 16; m <<= 1) {
#pragma unroll
    for (int mt = 0; mt < 2; ++mt)
#pragma unroll
      for (int reg = 0; reg < 4; ++reg) {
        f1p[mt][reg] += __shfl_xor(f1p[mt][reg], m);
        f2p[mt][reg] += __shfl_xor(f2p[mt][reg], m);
      }
  }
  if (m16 == 0) {
#pragma unroll
    for (int mt = 0; mt < 2; ++mt)
#pragma unroll
      for (int reg = 0; reg < 4; ++reg) {
        const int i = i0 + mt * 16 + q * 4 + reg;
        atomicAdd(&f1[i], f1p[mt][reg]);
        atomicAdd(&f2[i], f2p[mt][reg]);
      }
  }
}

// ---------------------------------------------------------------------------
// k3: Mstar = max_j f2[j]
// ---------------------------------------------------------------------------
__global__ __launch_bounds__(256) void k3_max(const float* __restrict__ f2,
                                              float* __restrict__ Mstar) {
  __shared__ float red[4];
  const int t = threadIdx.x;
  float m = -1e30f;
  for (int i = t; i < NN; i += 256) m = fmaxf(m, f2[i]);
#pragma unroll
  for (int d = 1; d < 64; d <<= 1) m = fmaxf(m, __shfl_xor(m, d));
  if ((t & 63) == 0) red[t >> 6] = m;
  __syncthreads();
  if (t == 0) *Mstar = fmaxf(fmaxf(red[0], red[1]), fmaxf(red[2], red[3]));
}

// ---------------------------------------------------------------------------
// k4: fused masked-softmax GEMM partial (j-split x4).
// BM=64 rows/block, all 256 cols; K-step 32 j. adj comes from the packed
// bitmask (1 uint32 per row per step). B fragments load DIRECTLY from the
// fragment-major whb (bf16x8/lane, coalesced 1KB/wave, L2-resident). Only
// the P tile (5 KB) round-trips LDS.
// ---------------------------------------------------------------------------
__global__ __launch_bounds__(256) void k4_attn(
    const unsigned* __restrict__ mask, const bf16* __restrict__ whb,
    const float* __restrict__ f1, const float* __restrict__ f2,
    const float* __restrict__ Mstar, const float* __restrict__ ba_p,
    float* __restrict__ acc_part, float* __restrict__ l_part) {
  __shared__ bf16 Pl[64 * 40];
  const int t = threadIdx.x;
  const int lane = t & 63, w = t >> 6;
  const int m16 = lane & 15, q = lane >> 4;
  const int rb = blockIdx.x, s = blockIdx.y;
  const int i0 = rb * 64;
  const int rloc = t >> 2;      // row this thread scores (0..63)
  const int jj = (t & 3) * 8;   // 8 j's within the 32-wide k-step

  const float ba = *ba_p;
  const float Ms = *Mstar;
  const float ci = f1[i0 + rloc] + ba;
  float sh = ci + Ms;
  sh = fmaxf(sh, 0.2f * sh);    // LeakyReLU(c_i + Mstar) >= row max

  const f32x4 z4 = {0.f, 0.f, 0.f, 0.f};
  f32x4 acc[4][4];  // [mt][cc]
#pragma unroll
  for (int mt = 0; mt < 4; ++mt)
#pragma unroll
    for (int cc = 0; cc < 4; ++cc) acc[mt][cc] = z4;
  float lreg = 0.f;

  const unsigned* mrow = mask + (size_t)(i0 + rloc) * (NN / 32);
  const int sbase = s * JCHUNK;

  for (int kt = 0; kt < JCHUNK / 32; ++kt) {
    const int j0 = sbase + kt * 32;
    const unsigned mw = mrow[j0 >> 5];
    f32x4 s4a = *(const f32x4*)(f2 + j0 + jj);
    f32x4 s4b = *(const f32x4*)(f2 + j0 + jj + 4);
    // B fragments: direct global, element (j,n) at jblk*8192 + n*32 + (j&31)
    const size_t bbase = (size_t)(j0 >> 5) * (FO * 32) + q * 8;
    bf16x8 bfr[4];
#pragma unroll
    for (int cc = 0; cc < 4; ++cc)
      bfr[cc] = *(const bf16x8*)(whb + bbase + (size_t)((w * 4 + cc) * 16 + m16) * 32);
    float pv[8];
#pragma unroll
    for (int x = 0; x < 4; ++x) {
      float arg = ci + s4a[x];
      float e = fmaxf(arg, 0.2f * arg);
      pv[x] = ((mw >> (jj + x)) & 1u) ? __expf(e - sh) : 0.f;
    }
#pragma unroll
    for (int x = 0; x < 4; ++x) {
      float arg = ci + s4b[x];
      float e = fmaxf(arg, 0.2f * arg);
      pv[4 + x] = ((mw >> (jj + 4 + x)) & 1u) ? __expf(e - sh) : 0.f;
    }
#pragma unroll
    for (int x = 0; x < 8; ++x) lreg += pv[x];
    __syncthreads();  // previous iteration's Pl reads done
    bf16x8 pb;
#pragma unroll
    for (int x = 0; x < 8; ++x) pb[x] = (bf16)pv[x];
    *(bf16x8*)&Pl[rloc * 40 + jj] = pb;
    __syncthreads();
#pragma unroll
    for (int mt = 0; mt < 4; ++mt) {
      bf16x8 af = *(const bf16x8*)&Pl[(mt * 16 + m16) * 40 + q * 8];
#pragma unroll
      for (int cc = 0; cc < 4; ++cc)
        acc[mt][cc] = __builtin_amdgcn_mfma_f32_16x16x32_bf16(af, bfr[cc], acc[mt][cc], 0, 0, 0);
    }
  }
  // row-sum partial: 4 threads share a row
  lreg += __shfl_xor(lreg, 1);
  lreg += __shfl_xor(lreg, 2);
  if ((t & 3) == 0) l_part[(size_t)s * NN + i0 + rloc] = lreg;
  // C/D: col = lane&15 (n), row = q*4+reg
  float* ap = acc_part + (size_t)s * ((size_t)NN * FO);
#pragma unroll
  for (int mt = 0; mt < 4; ++mt) {
#pragma unroll
    for (int cc = 0; cc < 4; ++cc) {
      const int n = (w * 4 + cc) * 16 + m16;
#pragma unroll
      for (int reg = 0; reg < 4; ++reg) {
        const int r = i0 + mt * 16 + q * 4 + reg;
        ap[(size_t)r * FO + n] = acc[mt][cc][reg];
      }
    }
  }
}

// ---------------------------------------------------------------------------
// k5: out[i][n] = (sum_s acc_part[s][i][n]) / (sum_s l_part[s][i])
// ---------------------------------------------------------------------------
__global__ __launch_bounds__(256) void k5_reduce(
    const float* __restrict__ accp, const float* __restrict__ lp,
    float* __restrict__ out) {
  const int idx = blockIdx.x * 256 + threadIdx.x;
  const int i = idx >> 6, n4 = (idx & 63) * 4;
  f32x4 sum = {0.f, 0.f, 0.f, 0.f};
  float l = 0.f;
#pragma unroll
  for (int s = 0; s < NSPLIT; ++s) {
    sum += *(const f32x4*)&accp[(size_t)s * ((size_t)NN * FO) + (size_t)i * FO + n4];
    l += lp[s * NN + i];
  }
  const float rl = 1.0f / l;
  f32x4 o = sum * rl;
  *(f32x4*)&out[(size_t)i * FO + n4] = o;
}

// ---------------------------------------------------------------------------
// Workspace layout:
//   [0, 4MB)        whb  (bf16 Wh, fragment-major)
//   4MB             f1   (32 KB)
//   +32KB           f2   (32 KB)
//   +64KB           Mstar (256 B)
//   +64KB+256       acc_part[4][8192][256] f32 (32 MB)
//   +...            l_part[4][8192] f32 (128 KB)
//   +...            mask (8 MB)
//   +...            wth (256 KB), wtl (256 KB)
// total ~44.7 MB
// ---------------------------------------------------------------------------
extern "C" void kernel_launch(void* const* d_in, const int* in_sizes, int n_in,
                              void* d_out, int out_size, void* d_ws, size_t ws_size,
                              hipStream_t stream) {
  const float* h   = (const float*)d_in[0];
  const int*   adj = (const int*)d_in[1];
  const float* W   = (const float*)d_in[2];
  const float* bW  = (const float*)d_in[3];
  const float* a1  = (const float*)d_in[4];
  const float* a2  = (const float*)d_in[5];
  const float* ba  = (const float*)d_in[6];
  float* out = (float*)d_out;

  char* ws = (char*)d_ws;
  bf16* whb   = (bf16*)ws;
  float* f1   = (float*)(ws + 4u * 1024 * 1024);
  float* f2   = (float*)(ws + 4u * 1024 * 1024 + 32 * 1024);
  float* Mst  = (float*)(ws + 4u * 1024 * 1024 + 64 * 1024);
  float* accp = (float*)(ws + 4u * 1024 * 1024 + 64 * 1024 + 256);
  float* lp   = accp + (size_t)NSPLIT * NN * FO;
  unsigned* mask = (unsigned*)((char*)lp + (size_t)NSPLIT * NN * 4);
  bf16* wth   = (bf16*)((char*)mask + (size_t)NN * (NN / 32) * 4);
  bf16* wtl   = wth + (size_t)FO * FI;

  hipMemsetAsync(f1, 0, 64 * 1024, stream);  // zero f1+f2 (atomic targets)

  k0_pack<<<NN * (NN / 32) / 256, 256, 0, stream>>>(adj, mask);
  kw_split<<<FI * FO / 256, 256, 0, stream>>>(W, wth, wtl);
  k1_gemm<<<dim3(NN / 32, 2), 256, 0, stream>>>(h, wth, wtl, bW, a1, a2, whb, f1, f2);
  k3_max<<<1, 256, 0, stream>>>(f2, Mst);
  k4_attn<<<dim3(NN / 64, NSPLIT), 256, 0, stream>>>(mask, whb, f1, f2, Mst, ba, accp, lp);
  k5_reduce<<<(NN * FO / 4) / 256, 256, 0, stream>>>(accp, lp, out);
}